// Round 16
// baseline (45.439 us; speedup 1.0000x reference)
//
#include <hip/hip_runtime.h>
#include <hip/hip_bf16.h>

// LLoCaAttention, MI355X. Two-kernel structure:
//  1) rot_cast: rotation (blockdiag(1,Q^T)) + f32->bf16, LOAD-BALANCED:
//     256 blocks x 256 threads, every thread processes 2 rows (K-pair or
//     V-key-pair) -- R15's 64 V-blocks ran 4x longer than the 256 K-blocks.
//     K: [key][32ch], granule gi stored at gi^(n&3) (bank-spread, R15).
//     V: transposed+permuted, granule stored at g^(ch&15) (R13).
//  2) lloca_attn: NT=4 (64 q/wave): halves the per-CU LDS fragment-read
//     floor (the dominant pipe) vs NT=2 -- fragments amortize over 4 q-tiles.
//     Grid 256 (1 block/CU), async gload_lds staging, R13 pipeline order:
//     vmcnt(0) -> barrier -> STAGE(i+1) -> compute(i). BK=256, m=0 softmax,
//     ones-MFMA l-sum, XCD-swizzled blockIdx.

#define NB 4
#define NH 8
#define NS 2048
#define NC 32

typedef float f32x4 __attribute__((ext_vector_type(4)));
typedef short s16x8 __attribute__((ext_vector_type(8)));
typedef short s16x4 __attribute__((ext_vector_type(4)));

// 1/(C * ln2): fold softmax 1/C scale and log2-domain conversion into Q.
#define QSCALE 0.04511260931463978f

__device__ __forceinline__ short f2bf(float f) {  // RTNE f32 -> bf16 bits
  union { float f; unsigned u; } c; c.f = f;
  return (short)((c.u + 0x7FFFu + ((c.u >> 16) & 1u)) >> 16);
}

__device__ __forceinline__ void gload16(const void* g, void* l) {
  // async global->LDS, 16 B/lane; LDS dst = wave-uniform base + lane*16.
  __builtin_amdgcn_global_load_lds(
      (const __attribute__((address_space(1))) unsigned int*)g,
      (__attribute__((address_space(3))) unsigned int*)l, 16, 0, 0);
}

__device__ __forceinline__ void load_Q3(const float* __restrict__ F, int b, int n,
                                        float q9[9]) {
  const float* p = F + ((size_t)(b * NS + n)) * 16 + 5;  // rows/cols 1..3 of 4x4
  q9[0] = p[0]; q9[1] = p[1]; q9[2] = p[2];
  q9[3] = p[4]; q9[4] = p[5]; q9[5] = p[6];
  q9[6] = p[8]; q9[7] = p[9]; q9[8] = p[10];
}

// spatial part (elements 1..3) <- Q^T * spatial   [input transform]
__device__ __forceinline__ void rotT(const float q9[9], f32x4& v) {
  const float x = v[1], y = v[2], z = v[3];
  v[1] = q9[0] * x + q9[3] * y + q9[6] * z;
  v[2] = q9[1] * x + q9[4] * y + q9[7] * z;
  v[3] = q9[2] * x + q9[5] * y + q9[8] * z;
}

// spatial part <- Q * spatial     [output transform]
__device__ __forceinline__ void rotF(const float q9[9], f32x4& v) {
  const float x = v[1], y = v[2], z = v[3];
  v[1] = q9[0] * x + q9[1] * y + q9[2] * z;
  v[2] = q9[3] * x + q9[4] * y + q9[5] * z;
  v[3] = q9[6] * x + q9[7] * y + q9[8] * z;
}

// ---- pass 1 (balanced): tid<32768: 2 K rows; else: 2 V keys. 256 blocks. ----
__launch_bounds__(256)
__global__ void rot_cast(const float* __restrict__ Kg,
                         const float* __restrict__ Vg,
                         const float* __restrict__ Fg,
                         unsigned short* __restrict__ Kbf,
                         unsigned short* __restrict__ Vt) {
  const int gid = blockIdx.x * 256 + threadIdx.x;  // 65536 threads
  if (gid < 32768) {
    // K: rows 2*gid, 2*gid+1 (contiguous 256 B read, coalesced).
#pragma unroll
    for (int rr = 0; rr < 2; rr++) {
      const int r = 2 * gid + rr;          // (b*H + h)*N + n
      const int n = r & (NS - 1);
      const int b = r >> 14;
      const float* p = Kg + (size_t)r * NC;
      f32x4 c[8];
#pragma unroll
      for (int i = 0; i < 8; i++) c[i] = *(const f32x4*)(p + 4 * i);
      float q9[9]; load_Q3(Fg, b, n, q9);
#pragma unroll
      for (int i = 4; i < 8; i++) rotT(q9, c[i]);   // four-vectors (ch 16..31)
      unsigned short* o = Kbf + (size_t)r * NC;
      const int ks = n & 3;
#pragma unroll
      for (int i = 0; i < 8; i += 2) {
        s16x8 w;
#pragma unroll
        for (int e = 0; e < 4; e++) {
          w[e]     = f2bf(c[i][e]);
          w[4 + e] = f2bf(c[i + 1][e]);
        }
        *(s16x8*)(o + (((i >> 1) ^ ks) << 3)) = w;
      }
    }
  } else {
    // V: keys K0, K0+1 -> transposed+permuted+swizzled. Two consecutive keys
    // occupy consecutive pos in the same granule (pos = newsub*4 + (K0&3),
    // K0 even) -> one u32 store per channel.
    const int u  = gid - 32768;           // 0..32767 key-pairs
    const int bh = u >> 10;               // 1024 pairs per bh
    const int b  = bh >> 3;
    const int K0 = (u & 1023) << 1;       // first key (even)
    const float* vsrc = Vg + ((size_t)bh * NS + K0) * NC;
    unsigned short o0[32], o1[32];
#pragma unroll
    for (int k = 0; k < 2; k++) {
      f32x4 c[8];
#pragma unroll
      for (int i = 0; i < 8; i++) c[i] = *(const f32x4*)(vsrc + (size_t)k * NC + 4 * i);
      float q9[9]; load_Q3(Fg, b, K0 + k, q9);
#pragma unroll
      for (int i = 4; i < 8; i++) rotT(q9, c[i]);
      unsigned short* dst = k ? o1 : o0;
#pragma unroll
      for (int i = 0; i < 8; i++)
#pragma unroll
        for (int e = 0; e < 4; e++) dst[i * 4 + e] = (unsigned short)f2bf(c[i][e]);
    }
    const int c7     = K0 & 127;
    const int sub4   = (c7 & 31) >> 2;
    const int newsub = (sub4 & 3) * 2 + (sub4 >> 2);
    const int pos    = (c7 >> 5) * 32 + newsub * 4 + (K0 & 3);
    const int gpos   = pos >> 3;
    const int rem    = pos & 7;
    unsigned short* ob = Vt + (size_t)bh * (NS * NC) + (K0 >> 7) * 4096;
#pragma unroll
    for (int ch = 0; ch < 32; ch++) {
      unsigned uu = (unsigned)o0[ch] | ((unsigned)o1[ch] << 16);
      *(unsigned*)(ob + ch * 128 + ((gpos ^ (ch & 15)) << 3) + rem) = uu;
    }
  }
}

// ---- pass 2: flash attention, NT=4, pipelined async gload_lds staging ----
__launch_bounds__(256, 1)
__global__ void lloca_attn(const float* __restrict__ Qg,
                           const unsigned short* __restrict__ Kbf,
                           const unsigned short* __restrict__ Vt,
                           const float* __restrict__ Fg,
                           float* __restrict__ Og) {
  // Linear (DMA-filled) double-buffered BK=256 tiles.
  // K: [256 keys][32 ch, granule-swizzled]. V: [chunk][32 ch][128 swizzled].
  __shared__ __align__(16) unsigned short Klds[2][256 * 32];      // 16 KB each
  __shared__ __align__(16) unsigned short Vlds[2][2 * 32 * 128];  // 16 KB each

  const int tid  = threadIdx.x;   // 0..255 (4 waves)
  const int lane = tid & 63;
  const int wv   = tid >> 6;
  const int g    = lane >> 4;   // lane group 0..3
  const int lq   = lane & 15;   // query-within-tile (MFMA col)

  // XCD swizzle: XCD x gets blocks [x*32, x*32+32) = 4 bh -> 2 MB ⊂ its L2.
  const int bid = blockIdx.x;   // 256
  const int blk = (bid & 7) * 32 + (bid >> 3);
  const int b   = blk >> 6;     // 256 = B(2b) H(3b) qb(3b)
  const int h   = (blk >> 3) & 7;
  const int qb  = blk & 7;

  const size_t bhr = (size_t)(b * NH + h) * NS;
  const unsigned short* Kp  = Kbf + bhr * NC;
  const unsigned short* Vtp = Vt  + bhr * NC;
  float*                Op  = Og  + bhr * NC;

  const int qbase = qb * 256 + wv * 64;  // this wave's 64 queries (4 tiles of 16)

  const f32x4 zero4 = {0.f, 0.f, 0.f, 0.f};
  const short ONE = (short)0x3F80;  // bf16 1.0
  const s16x8 ones8 = {ONE, ONE, ONE, ONE, ONE, ONE, ONE, ONE};

  // ---- prologue: load + rotate + scale + pack own Q fragments ----
  s16x8 qfrag[4];
  f32x4 acc[4][2];
  f32x4 accL[4];
#pragma unroll
  for (int t = 0; t < 4; t++) {
    const int qi = qbase + t * 16 + lq;
    const float* qp = Qg + (bhr + qi) * NC + g * 8;  // slot (g,j) <-> ch 8g+j
    f32x4 a = *(const f32x4*)qp;
    f32x4 c = *(const f32x4*)(qp + 4);
    if (g >= 2) {  // g==2: vectors 0,1 ; g==3: vectors 2,3
      float q9[9]; load_Q3(Fg, b, qi, q9);
      rotT(q9, a);
      rotT(q9, c);
    }
#pragma unroll
    for (int e = 0; e < 4; e++) {
      qfrag[t][e]     = f2bf(a[e] * QSCALE);
      qfrag[t][4 + e] = f2bf(c[e] * QSCALE);
    }
    acc[t][0] = zero4;
    acc[t][1] = zero4;
    accL[t]   = zero4;
  }

  // staging: per 256-key tile each wave DMAs 4 KB of K and 4 KB of V
  // (8 gload16, 1 KB wave-wide each). Linear copies of 8192-ush tiles.
  const int lel = lane * 8;

#define STAGE(buf, i)                                                          \
  do {                                                                         \
    const size_t goff = (size_t)(i) * 8192;                                    \
    const unsigned short* ks = Kp + goff + wv * 2048 + lel;                    \
    const unsigned short* vs = Vtp + goff + wv * 2048 + lel;                   \
    unsigned short* kd = &Klds[buf][wv * 2048];                                \
    unsigned short* vd = &Vlds[buf][wv * 2048];                                \
    gload16(ks, kd);               gload16(ks + 512, kd + 512);                \
    gload16(ks + 1024, kd + 1024); gload16(ks + 1536, kd + 1536);              \
    gload16(vs, vd);               gload16(vs + 512, vd + 512);                \
    gload16(vs + 1024, vd + 1024); gload16(vs + 1536, vd + 1536);              \
  } while (0)

  STAGE(0, 0);

  const int ksw = (g ^ (lq & 3)) << 3;  // K granule un-swizzle for this lane

  const int NTT = NS / 256;  // 8 tiles
  for (int i = 0; i < NTT; i++) {
    const int cur = i & 1;
    // wait MY tile-i DMAs (only ones in flight; had a full compute to land),
    // then barrier: every wave drained its own share -> tile i fully resident.
    asm volatile("s_waitcnt vmcnt(0)" ::: "memory");
    __builtin_amdgcn_s_barrier();
    __builtin_amdgcn_sched_barrier(0);  // keep ds_reads below the barrier
    if (i + 1 < NTT) STAGE(cur ^ 1, i + 1);  // flies across compute(i)
    __builtin_amdgcn_s_setprio(1);
#pragma unroll
    for (int kgi = 0; kgi < 8; kgi++) {
      const int kgb = kgi * 32;
      const s16x8 kf0 = *(const s16x8*)&Klds[cur][(kgb + lq) * 32 + ksw];
      const s16x8 kf1 = *(const s16x8*)&Klds[cur][(kgb + 16 + lq) * 32 + ksw];
      const int vbase2 = (kgb >> 7) * 4096;        // 128-key chunk
      const int kgb7   = kgb & 127;
      const int vsw    = ((((kgb7) >> 3) + g) ^ lq) << 3;  // granule XOR swizzle
      const s16x8 va0 = *(const s16x8*)&Vlds[cur][vbase2 + lq * 128 + vsw];
      const s16x8 va1 = *(const s16x8*)&Vlds[cur][vbase2 + (16 + lq) * 128 + vsw];
#pragma unroll
      for (int t = 0; t < 4; t++) {
        // S^T = K_chunk * Q : lane holds scores for q=lq, keys kgb+4g+r / kgb+16+4g+r
        f32x4 s0 = __builtin_amdgcn_mfma_f32_16x16x32_bf16(kf0, qfrag[t], zero4, 0, 0, 0);
        f32x4 s1 = __builtin_amdgcn_mfma_f32_16x16x32_bf16(kf1, qfrag[t], zero4, 0, 0, 0);
        // m = 0 fixed: scores are q.k/C in log2 units; f32 exp2 overflow-safe.
        float p0 = __builtin_amdgcn_exp2f(s0[0]);
        float p1 = __builtin_amdgcn_exp2f(s0[1]);
        float p2 = __builtin_amdgcn_exp2f(s0[2]);
        float p3 = __builtin_amdgcn_exp2f(s0[3]);
        float p4 = __builtin_amdgcn_exp2f(s1[0]);
        float p5 = __builtin_amdgcn_exp2f(s1[1]);
        float p6 = __builtin_amdgcn_exp2f(s1[2]);
        float p7 = __builtin_amdgcn_exp2f(s1[3]);
        union { __hip_bfloat162 h2v[4]; s16x8 v; } pk;
        pk.h2v[0] = __float22bfloat162_rn(make_float2(p0, p1));
        pk.h2v[1] = __float22bfloat162_rn(make_float2(p2, p3));
        pk.h2v[2] = __float22bfloat162_rn(make_float2(p4, p5));
        pk.h2v[3] = __float22bfloat162_rn(make_float2(p6, p7));
        // l-sum on the matrix pipe: every C row of (ones * P) = sum_k P[k][lq]
        accL[t]   = __builtin_amdgcn_mfma_f32_16x16x32_bf16(ones8, pk.v, accL[t], 0, 0, 0);
        acc[t][0] = __builtin_amdgcn_mfma_f32_16x16x32_bf16(va0,   pk.v, acc[t][0], 0, 0, 0);
        acc[t][1] = __builtin_amdgcn_mfma_f32_16x16x32_bf16(va1,   pk.v, acc[t][1], 0, 0, 0);
      }
    }
    __builtin_amdgcn_s_setprio(0);
  }

  // ---- epilogue: normalize, rotate output vector g by Q_query, store.
  // O^T: col=q=lq, rows: ch 4g+r (acc0, scalars) / 16+4g+r (acc1, four-vector g)
#pragma unroll
  for (int t = 0; t < 4; t++) {
    const float inv = 1.0f / accL[t][0];
    const int qi = qbase + t * 16 + lq;
    float* op = Op + (size_t)qi * NC;
    f32x4 o0, o1;
#pragma unroll
    for (int r = 0; r < 4; r++) {
      o0[r] = acc[t][0][r] * inv;
      o1[r] = acc[t][1][r] * inv;
    }
    float q9[9]; load_Q3(Fg, b, qi, q9);
    rotF(q9, o1);
    *(f32x4*)(op + g * 4)      = o0;
    *(f32x4*)(op + 16 + g * 4) = o1;
  }
}

extern "C" void kernel_launch(void* const* d_in, const int* in_sizes, int n_in,
                              void* d_out, int out_size, void* d_ws, size_t ws_size,
                              hipStream_t stream) {
  (void)in_sizes; (void)n_in; (void)ws_size; (void)out_size;
  const float* q = (const float*)d_in[0];
  const float* k = (const float*)d_in[1];
  const float* v = (const float*)d_in[2];
  const float* f = (const float*)d_in[3];
  float* o = (float*)d_out;

  const size_t NEL = (size_t)NB * NH * NS * NC;  // 2,097,152 elements
  unsigned short* kbf = (unsigned short*)d_ws;   // 4 MB
  unsigned short* vt  = kbf + NEL;               // 4 MB

  hipLaunchKernelGGL(rot_cast, dim3(256), dim3(256), 0, stream,
                     k, v, f, kbf, vt);
  hipLaunchKernelGGL(lloca_attn, dim3(256), dim3(256), 0, stream,
                     q, kbf, vt, f, o);
}

// Round 17
// 36.240 us; speedup vs baseline: 1.2538x; 1.2538x over previous
//
#include <hip/hip_runtime.h>
#include <hip/hip_bf16.h>

// LLoCaAttention, MI355X. Two-kernel structure:
//  1) rot_cast: rotation (blockdiag(1,Q^T)) + f32->bf16, LOAD-BALANCED
//     (R16): 256 blocks x 256 threads, every thread 2 rows (K-pair or
//     V-key-pair), fully coalesced.
//     K: [key][32ch], granule gi stored at gi^(n&3) (bank-spread, R15).
//     V: transposed+permuted, granule stored at gpos^(ch&15) (R13).
//  2) lloca_attn: EXACT R15 kernel (best: 40.2us): NT=2, grid 512, 2
//     blocks/CU, async gload_lds staging, pipeline order
//     vmcnt(0) -> barrier -> STAGE(i+1) -> compute(i), BK=256, m=0 softmax,
//     ones-MFMA l-sum, XCD-swizzled blockIdx.

#define NB 4
#define NH 8
#define NS 2048
#define NC 32

typedef float f32x4 __attribute__((ext_vector_type(4)));
typedef short s16x8 __attribute__((ext_vector_type(8)));
typedef short s16x4 __attribute__((ext_vector_type(4)));

// 1/(C * ln2): fold softmax 1/C scale and log2-domain conversion into Q.
#define QSCALE 0.04511260931463978f

__device__ __forceinline__ short f2bf(float f) {  // RTNE f32 -> bf16 bits
  union { float f; unsigned u; } c; c.f = f;
  return (short)((c.u + 0x7FFFu + ((c.u >> 16) & 1u)) >> 16);
}

__device__ __forceinline__ void gload16(const void* g, void* l) {
  // async global->LDS, 16 B/lane; LDS dst = wave-uniform base + lane*16.
  __builtin_amdgcn_global_load_lds(
      (const __attribute__((address_space(1))) unsigned int*)g,
      (__attribute__((address_space(3))) unsigned int*)l, 16, 0, 0);
}

__device__ __forceinline__ void load_Q3(const float* __restrict__ F, int b, int n,
                                        float q9[9]) {
  const float* p = F + ((size_t)(b * NS + n)) * 16 + 5;  // rows/cols 1..3 of 4x4
  q9[0] = p[0]; q9[1] = p[1]; q9[2] = p[2];
  q9[3] = p[4]; q9[4] = p[5]; q9[5] = p[6];
  q9[6] = p[8]; q9[7] = p[9]; q9[8] = p[10];
}

// spatial part (elements 1..3) <- Q^T * spatial   [input transform]
__device__ __forceinline__ void rotT(const float q9[9], f32x4& v) {
  const float x = v[1], y = v[2], z = v[3];
  v[1] = q9[0] * x + q9[3] * y + q9[6] * z;
  v[2] = q9[1] * x + q9[4] * y + q9[7] * z;
  v[3] = q9[2] * x + q9[5] * y + q9[8] * z;
}

// spatial part <- Q * spatial     [output transform]
__device__ __forceinline__ void rotF(const float q9[9], f32x4& v) {
  const float x = v[1], y = v[2], z = v[3];
  v[1] = q9[0] * x + q9[1] * y + q9[2] * z;
  v[2] = q9[3] * x + q9[4] * y + q9[5] * z;
  v[3] = q9[6] * x + q9[7] * y + q9[8] * z;
}

// ---- pass 1 (balanced): gid<32768: 2 K rows; else: 2 V keys. 256 blocks. ----
__launch_bounds__(256)
__global__ void rot_cast(const float* __restrict__ Kg,
                         const float* __restrict__ Vg,
                         const float* __restrict__ Fg,
                         unsigned short* __restrict__ Kbf,
                         unsigned short* __restrict__ Vt) {
  const int gid = blockIdx.x * 256 + threadIdx.x;  // 65536 threads
  if (gid < 32768) {
    // K: rows 2*gid, 2*gid+1 (contiguous 256 B read, coalesced).
#pragma unroll
    for (int rr = 0; rr < 2; rr++) {
      const int r = 2 * gid + rr;          // (b*H + h)*N + n
      const int n = r & (NS - 1);
      const int b = r >> 14;
      const float* p = Kg + (size_t)r * NC;
      f32x4 c[8];
#pragma unroll
      for (int i = 0; i < 8; i++) c[i] = *(const f32x4*)(p + 4 * i);
      float q9[9]; load_Q3(Fg, b, n, q9);
#pragma unroll
      for (int i = 4; i < 8; i++) rotT(q9, c[i]);   // four-vectors (ch 16..31)
      unsigned short* o = Kbf + (size_t)r * NC;
      const int ks = n & 3;
#pragma unroll
      for (int i = 0; i < 8; i += 2) {
        s16x8 w;
#pragma unroll
        for (int e = 0; e < 4; e++) {
          w[e]     = f2bf(c[i][e]);
          w[4 + e] = f2bf(c[i + 1][e]);
        }
        *(s16x8*)(o + (((i >> 1) ^ ks) << 3)) = w;
      }
    }
  } else {
    // V: keys K0, K0+1 -> transposed+permuted+swizzled. Two consecutive keys
    // occupy consecutive pos in the same granule (pos = newsub*4 + (K0&3),
    // K0 even) -> one u32 store per channel.
    const int u  = gid - 32768;           // 0..32767 key-pairs
    const int bh = u >> 10;               // 1024 pairs per bh
    const int b  = bh >> 3;
    const int K0 = (u & 1023) << 1;       // first key (even)
    const float* vsrc = Vg + ((size_t)bh * NS + K0) * NC;
    unsigned short o0[32], o1[32];
#pragma unroll
    for (int k = 0; k < 2; k++) {
      f32x4 c[8];
#pragma unroll
      for (int i = 0; i < 8; i++) c[i] = *(const f32x4*)(vsrc + (size_t)k * NC + 4 * i);
      float q9[9]; load_Q3(Fg, b, K0 + k, q9);
#pragma unroll
      for (int i = 4; i < 8; i++) rotT(q9, c[i]);
      unsigned short* dst = k ? o1 : o0;
#pragma unroll
      for (int i = 0; i < 8; i++)
#pragma unroll
        for (int e = 0; e < 4; e++) dst[i * 4 + e] = (unsigned short)f2bf(c[i][e]);
    }
    const int c7     = K0 & 127;
    const int sub4   = (c7 & 31) >> 2;
    const int newsub = (sub4 & 3) * 2 + (sub4 >> 2);
    const int pos    = (c7 >> 5) * 32 + newsub * 4 + (K0 & 3);
    const int gpos   = pos >> 3;
    const int rem    = pos & 7;
    unsigned short* ob = Vt + (size_t)bh * (NS * NC) + (K0 >> 7) * 4096;
#pragma unroll
    for (int ch = 0; ch < 32; ch++) {
      unsigned uu = (unsigned)o0[ch] | ((unsigned)o1[ch] << 16);
      *(unsigned*)(ob + ch * 128 + ((gpos ^ (ch & 15)) << 3) + rem) = uu;
    }
  }
}

// ---- pass 2: flash attention (exact R15), pipelined async gload_lds ----
__launch_bounds__(256, 2)
__global__ void lloca_attn(const float* __restrict__ Qg,
                           const unsigned short* __restrict__ Kbf,
                           const unsigned short* __restrict__ Vt,
                           const float* __restrict__ Fg,
                           float* __restrict__ Og) {
  // Linear (DMA-filled) double-buffered BK=256 tiles.
  // K: [256 keys][32 ch, granule-swizzled]. V: [chunk][32 ch][128 swizzled].
  __shared__ __align__(16) unsigned short Klds[2][256 * 32];      // 16 KB each
  __shared__ __align__(16) unsigned short Vlds[2][2 * 32 * 128];  // 16 KB each

  const int tid  = threadIdx.x;   // 0..255 (4 waves)
  const int lane = tid & 63;
  const int wv   = tid >> 6;
  const int g    = lane >> 4;   // lane group 0..3
  const int lq   = lane & 15;   // query-within-tile (MFMA col)

  // XCD swizzle: XCD x gets works [x*64, x*64+64) = 4 bh -> 2 MB ⊂ its L2.
  const int bid = blockIdx.x;   // 512
  const int blk = (bid & 7) * 64 + (bid >> 3);
  const int b   = blk >> 7;
  const int h   = (blk >> 4) & 7;
  const int qb  = blk & 15;

  const size_t bhr = (size_t)(b * NH + h) * NS;
  const unsigned short* Kp  = Kbf + bhr * NC;
  const unsigned short* Vtp = Vt  + bhr * NC;
  float*                Op  = Og  + bhr * NC;

  const int qbase = qb * 128 + wv * 32;  // this wave's 32 queries (2 tiles of 16)

  const f32x4 zero4 = {0.f, 0.f, 0.f, 0.f};
  const short ONE = (short)0x3F80;  // bf16 1.0
  const s16x8 ones8 = {ONE, ONE, ONE, ONE, ONE, ONE, ONE, ONE};

  // ---- prologue: load + rotate + scale + pack own Q fragments ----
  s16x8 qfrag[2];
  f32x4 acc[2][2];
  f32x4 accL[2];
#pragma unroll
  for (int t = 0; t < 2; t++) {
    const int qi = qbase + t * 16 + lq;
    const float* qp = Qg + (bhr + qi) * NC + g * 8;  // slot (g,j) <-> ch 8g+j
    f32x4 a = *(const f32x4*)qp;
    f32x4 c = *(const f32x4*)(qp + 4);
    if (g >= 2) {  // g==2: vectors 0,1 ; g==3: vectors 2,3
      float q9[9]; load_Q3(Fg, b, qi, q9);
      rotT(q9, a);
      rotT(q9, c);
    }
#pragma unroll
    for (int e = 0; e < 4; e++) {
      qfrag[t][e]     = f2bf(a[e] * QSCALE);
      qfrag[t][4 + e] = f2bf(c[e] * QSCALE);
    }
    acc[t][0] = zero4;
    acc[t][1] = zero4;
    accL[t]   = zero4;
  }

  // staging: per 256-key tile each wave DMAs 4 KB of K and 4 KB of V
  // (8 gload16, 1 KB wave-wide each). Linear copies of 8192-ush tiles.
  const int lel = lane * 8;

#define STAGE(buf, i)                                                          \
  do {                                                                         \
    const size_t goff = (size_t)(i) * 8192;                                    \
    const unsigned short* ks = Kp + goff + wv * 2048 + lel;                    \
    const unsigned short* vs = Vtp + goff + wv * 2048 + lel;                   \
    unsigned short* kd = &Klds[buf][wv * 2048];                                \
    unsigned short* vd = &Vlds[buf][wv * 2048];                                \
    gload16(ks, kd);               gload16(ks + 512, kd + 512);                \
    gload16(ks + 1024, kd + 1024); gload16(ks + 1536, kd + 1536);              \
    gload16(vs, vd);               gload16(vs + 512, vd + 512);                \
    gload16(vs + 1024, vd + 1024); gload16(vs + 1536, vd + 1536);              \
  } while (0)

  STAGE(0, 0);

  const int ksw = (g ^ (lq & 3)) << 3;  // K granule un-swizzle for this lane

  const int NTT = NS / 256;  // 8 tiles
  for (int i = 0; i < NTT; i++) {
    const int cur = i & 1;
    // wait MY tile-i DMAs (only ones in flight; had a full compute to land),
    // then barrier: every wave drained its own share -> tile i fully resident.
    asm volatile("s_waitcnt vmcnt(0)" ::: "memory");
    __builtin_amdgcn_s_barrier();
    __builtin_amdgcn_sched_barrier(0);  // keep ds_reads below the barrier
    if (i + 1 < NTT) STAGE(cur ^ 1, i + 1);  // flies across compute(i)
    __builtin_amdgcn_s_setprio(1);
#pragma unroll
    for (int kgi = 0; kgi < 8; kgi++) {
      const int kgb = kgi * 32;
      const s16x8 kf0 = *(const s16x8*)&Klds[cur][(kgb + lq) * 32 + ksw];
      const s16x8 kf1 = *(const s16x8*)&Klds[cur][(kgb + 16 + lq) * 32 + ksw];
      const int vbase2 = (kgb >> 7) * 4096;        // 128-key chunk
      const int kgb7   = kgb & 127;
      const int vsw    = ((((kgb7) >> 3) + g) ^ lq) << 3;  // granule XOR swizzle
      const s16x8 va0 = *(const s16x8*)&Vlds[cur][vbase2 + lq * 128 + vsw];
      const s16x8 va1 = *(const s16x8*)&Vlds[cur][vbase2 + (16 + lq) * 128 + vsw];
#pragma unroll
      for (int t = 0; t < 2; t++) {
        // S^T = K_chunk * Q : lane holds scores for q=lq, keys kgb+4g+r / kgb+16+4g+r
        f32x4 s0 = __builtin_amdgcn_mfma_f32_16x16x32_bf16(kf0, qfrag[t], zero4, 0, 0, 0);
        f32x4 s1 = __builtin_amdgcn_mfma_f32_16x16x32_bf16(kf1, qfrag[t], zero4, 0, 0, 0);
        // m = 0 fixed: scores are q.k/C in log2 units; f32 exp2 overflow-safe.
        float p0 = __builtin_amdgcn_exp2f(s0[0]);
        float p1 = __builtin_amdgcn_exp2f(s0[1]);
        float p2 = __builtin_amdgcn_exp2f(s0[2]);
        float p3 = __builtin_amdgcn_exp2f(s0[3]);
        float p4 = __builtin_amdgcn_exp2f(s1[0]);
        float p5 = __builtin_amdgcn_exp2f(s1[1]);
        float p6 = __builtin_amdgcn_exp2f(s1[2]);
        float p7 = __builtin_amdgcn_exp2f(s1[3]);
        union { __hip_bfloat162 h2v[4]; s16x8 v; } pk;
        pk.h2v[0] = __float22bfloat162_rn(make_float2(p0, p1));
        pk.h2v[1] = __float22bfloat162_rn(make_float2(p2, p3));
        pk.h2v[2] = __float22bfloat162_rn(make_float2(p4, p5));
        pk.h2v[3] = __float22bfloat162_rn(make_float2(p6, p7));
        // l-sum on the matrix pipe: every C row of (ones * P) = sum_k P[k][lq]
        accL[t]   = __builtin_amdgcn_mfma_f32_16x16x32_bf16(ones8, pk.v, accL[t], 0, 0, 0);
        acc[t][0] = __builtin_amdgcn_mfma_f32_16x16x32_bf16(va0,   pk.v, acc[t][0], 0, 0, 0);
        acc[t][1] = __builtin_amdgcn_mfma_f32_16x16x32_bf16(va1,   pk.v, acc[t][1], 0, 0, 0);
      }
    }
    __builtin_amdgcn_s_setprio(0);
  }

  // ---- epilogue: normalize, rotate output vector g by Q_query, store.
  // O^T: col=q=lq, rows: ch 4g+r (acc0, scalars) / 16+4g+r (acc1, four-vector g)
#pragma unroll
  for (int t = 0; t < 2; t++) {
    const float inv = 1.0f / accL[t][0];
    const int qi = qbase + t * 16 + lq;
    float* op = Op + (size_t)qi * NC;
    f32x4 o0, o1;
#pragma unroll
    for (int r = 0; r < 4; r++) {
      o0[r] = acc[t][0][r] * inv;
      o1[r] = acc[t][1][r] * inv;
    }
    float q9[9]; load_Q3(Fg, b, qi, q9);
    rotF(q9, o1);
    *(f32x4*)(op + g * 4)      = o0;
    *(f32x4*)(op + 16 + g * 4) = o1;
  }
}

extern "C" void kernel_launch(void* const* d_in, const int* in_sizes, int n_in,
                              void* d_out, int out_size, void* d_ws, size_t ws_size,
                              hipStream_t stream) {
  (void)in_sizes; (void)n_in; (void)ws_size; (void)out_size;
  const float* q = (const float*)d_in[0];
  const float* k = (const float*)d_in[1];
  const float* v = (const float*)d_in[2];
  const float* f = (const float*)d_in[3];
  float* o = (float*)d_out;

  const size_t NEL = (size_t)NB * NH * NS * NC;  // 2,097,152 elements
  unsigned short* kbf = (unsigned short*)d_ws;   // 4 MB
  unsigned short* vt  = kbf + NEL;               // 4 MB

  hipLaunchKernelGGL(rot_cast, dim3(256), dim3(256), 0, stream,
                     k, v, f, kbf, vt);
  hipLaunchKernelGGL(lloca_attn, dim3(512), dim3(256), 0, stream,
                     q, kbf, vt, f, o);
}